// Round 20
// baseline (123.907 us; speedup 1.0000x reference)
//
#include <hip/hip_runtime.h>
#include <cstddef>

#define HIDDEN 768
#define NHEADS 12
#define HDIM   64
#define BATCH  2
#define SEQ    2048
#define NROWS  (BATCH*SEQ)   // 4096
#define LOG2E  1.4426950408889634f

typedef float f32x4  __attribute__((ext_vector_type(4)));
typedef float f32x16 __attribute__((ext_vector_type(16)));
typedef short bf16x8 __attribute__((ext_vector_type(8)));

__device__ __forceinline__ float fast_exp2(float x){   // v_exp_f32: D = 2^S0
    return __builtin_amdgcn_exp2f(x);
}

__device__ __forceinline__ unsigned short f2bf(float f){   // RNE (prep paths)
    unsigned u = __builtin_bit_cast(unsigned, f);
    u = u + 0x7FFFu + ((u >> 16) & 1u);
    return (unsigned short)(u >> 16);
}
__device__ __forceinline__ unsigned packbf2(float a, float b){ // (lo=a, hi=b), half-up
    unsigned ua = (__builtin_bit_cast(unsigned, a) + 0x8000u) >> 16;
    unsigned ub = (__builtin_bit_cast(unsigned, b) + 0x8000u) & 0xFFFF0000u;
    return ua | ub;
}
__device__ __forceinline__ unsigned cvtpk_bf16(float a, float b){ // HW pack (T12)
    unsigned r;
    asm("v_cvt_pk_bf16_f32 %0, %1, %2" : "=v"(r) : "v"(a), "v"(b));
    return r;
}

// async global->LDS, 16B per lane; lds base wave-uniform (lane i -> base+i*16)
__device__ __forceinline__ void gl_lds16(const unsigned short* g, unsigned short* l){
    __builtin_amdgcn_global_load_lds(
        (const __attribute__((address_space(1))) unsigned int*)g,
        (__attribute__((address_space(3))) unsigned int*)l, 16, 0, 0);
}

// ---------------------------------------------------------------------------
// Elementwise fp32 -> bf16
// ---------------------------------------------------------------------------
__global__ __launch_bounds__(256) void cvt_bf16(const float* __restrict__ in,
                                                unsigned short* __restrict__ out,
                                                int n4)
{
    const int i = blockIdx.x * 256 + threadIdx.x;
    if (i >= n4) return;
    const float4 v = reinterpret_cast<const float4*>(in)[i];
    ushort4 o;
    o.x = f2bf(v.x); o.y = f2bf(v.y); o.z = f2bf(v.z); o.w = f2bf(v.w);
    reinterpret_cast<ushort4*>(out)[i] = o;
}

// ---------------------------------------------------------------------------
// All four 768x768 fp32 W -> bf16 W^T in one launch (z = which matrix)
// ---------------------------------------------------------------------------
__global__ __launch_bounds__(256) void transpose_cvt4(const float* __restrict__ W0,
                                                      const float* __restrict__ W1,
                                                      const float* __restrict__ W2,
                                                      const float* __restrict__ W3,
                                                      unsigned short* __restrict__ T0,
                                                      unsigned short* __restrict__ T1,
                                                      unsigned short* __restrict__ T2,
                                                      unsigned short* __restrict__ T3)
{
    const int z = blockIdx.z;
    const float* W = (z == 0) ? W0 : (z == 1) ? W1 : (z == 2) ? W2 : W3;
    unsigned short* Wt = (z == 0) ? T0 : (z == 1) ? T1 : (z == 2) ? T2 : T3;

    __shared__ unsigned short t[64][66];
    const int k0 = blockIdx.y * 64, n0 = blockIdx.x * 64;
    const int row = threadIdx.x >> 2;
    const int c0  = (threadIdx.x & 3) * 16;
#pragma unroll
    for (int j = 0; j < 16; j += 4) {
        const float4 v = *reinterpret_cast<const float4*>(&W[(size_t)(k0 + row) * HIDDEN + n0 + c0 + j]);
        t[row][c0 + j + 0] = f2bf(v.x);
        t[row][c0 + j + 1] = f2bf(v.y);
        t[row][c0 + j + 2] = f2bf(v.z);
        t[row][c0 + j + 3] = f2bf(v.w);
    }
    __syncthreads();
#pragma unroll
    for (int j = 0; j < 16; j += 4) {
        ushort4 o;
        o.x = t[c0 + j + 0][row];
        o.y = t[c0 + j + 1][row];
        o.z = t[c0 + j + 2][row];
        o.w = t[c0 + j + 3][row];
        *reinterpret_cast<ushort4*>(&Wt[(size_t)(n0 + row) * HIDDEN + k0 + c0 + j]) = o;
    }
}

// ---------------------------------------------------------------------------
// bf16 MFMA GEMM — EXACT round-13 structure (single-buffered, proven).
// ---------------------------------------------------------------------------
__device__ __forceinline__ void gemm_body(const unsigned short* __restrict__ A,
                                          const unsigned short* __restrict__ Wt,
                                          const float* __restrict__ bias,
                                          void* __restrict__ Cout, int mode,
                                          float scale,
                                          unsigned short* As, unsigned short* Bs)
{
    const int tid = threadIdx.x;
    const int l = tid & 63, w = tid >> 6;
    const int wm = w >> 1, wn = w & 1;
    const int l15 = l & 15, lg = l >> 4;
    const int srow = l >> 3, sslot = l & 7;
    const int m0 = blockIdx.y * 64, n0 = blockIdx.x * 96;

    f32x4 acc[2][3] = {};

    for (int k0 = 0; k0 < HIDDEN; k0 += 64) {
        __syncthreads();
#pragma unroll
        for (int a = 0; a < 2; ++a) {
            const int row = (a * 4 + w) * 8 + srow;
            const int sl = sslot ^ (row & 7);
            gl_lds16(&A[(size_t)(m0 + row) * HIDDEN + k0 + sl * 8], &As[(a * 4 + w) * 512]);
        }
#pragma unroll
        for (int b = 0; b < 3; ++b) {
            const int row = (b * 4 + w) * 8 + srow;
            const int sl = sslot ^ (row & 7);
            gl_lds16(&Wt[(size_t)(n0 + row) * HIDDEN + k0 + sl * 8], &Bs[(b * 4 + w) * 512]);
        }
        __syncthreads();

#pragma unroll
        for (int kk = 0; kk < 2; ++kk) {
            bf16x8 af[2], bfr[3];
#pragma unroll
            for (int mi = 0; mi < 2; ++mi) {
                const int r = wm * 32 + mi * 16 + l15;
                af[mi] = *reinterpret_cast<const bf16x8*>(&As[r * 64 + ((lg * 8 + kk * 32) ^ ((r & 7) << 3))]);
            }
#pragma unroll
            for (int ni = 0; ni < 3; ++ni) {
                const int r = wn * 48 + ni * 16 + l15;
                bfr[ni] = *reinterpret_cast<const bf16x8*>(&Bs[r * 64 + ((lg * 8 + kk * 32) ^ ((r & 7) << 3))]);
            }
#pragma unroll
            for (int mi = 0; mi < 2; ++mi)
#pragma unroll
                for (int ni = 0; ni < 3; ++ni)
                    acc[mi][ni] = __builtin_amdgcn_mfma_f32_16x16x32_bf16(af[mi], bfr[ni], acc[mi][ni], 0, 0, 0);
        }
    }

#pragma unroll
    for (int mi = 0; mi < 2; ++mi) {
#pragma unroll
        for (int ni = 0; ni < 3; ++ni) {
#pragma unroll
            for (int rr = 0; rr < 4; ++rr) {
                const int row = m0 + wm * 32 + mi * 16 + lg * 4 + rr;
                const int col = n0 + wn * 48 + ni * 16 + l15;
                const float v = (acc[mi][ni][rr] + bias[col]) * scale;
                if (mode == 0) {
                    const int b = row >> 11, s = row & (SEQ - 1);
                    const int hh = col >> 6, d = col & (HDIM - 1);
                    ((unsigned short*)Cout)[(((size_t)b * NHEADS + hh) * SEQ + s) * HDIM + d] = f2bf(v);
                } else if (mode == 1) {
                    const int b = row >> 11, s = row & (SEQ - 1);
                    const int hh = col >> 6, d = col & (HDIM - 1);
                    ((unsigned short*)Cout)[(((size_t)b * NHEADS + hh) * HDIM + d) * SEQ + s] = f2bf(v);
                } else {
                    ((float*)Cout)[(size_t)row * HIDDEN + col] = v;
                }
            }
        }
    }
}

// Fused Q/K/V projection: blockIdx.z selects weight/bias/output/mode/scale.
__global__ __launch_bounds__(256) void qkv_gemm(const unsigned short* __restrict__ A,
                                                const unsigned short* __restrict__ Wqt,
                                                const unsigned short* __restrict__ Wkt,
                                                const unsigned short* __restrict__ Wvt,
                                                const float* __restrict__ bq,
                                                const float* __restrict__ bk,
                                                const float* __restrict__ bv,
                                                unsigned short* __restrict__ Qb,
                                                unsigned short* __restrict__ Kb,
                                                unsigned short* __restrict__ Vtb)
{
    __shared__ unsigned short As[64 * 64];
    __shared__ unsigned short Bs[96 * 64];
    const int z = blockIdx.z;
    const unsigned short* Wt = (z == 0) ? Wqt : (z == 1) ? Wkt : Wvt;
    const float* bias = (z == 0) ? bq : (z == 1) ? bk : bv;
    void* out = (z == 0) ? (void*)Qb : (z == 1) ? (void*)Kb : (void*)Vtb;
    const int mode = (z == 2) ? 1 : 0;
    const float scale = (z == 0) ? LOG2E : 1.0f;
    gemm_body(A, Wt, bias, out, mode, scale, As, Bs);
}

// Output projection (fp32 out).
__global__ __launch_bounds__(256) void out_gemm(const unsigned short* __restrict__ A,
                                                const unsigned short* __restrict__ Wt,
                                                const float* __restrict__ bias,
                                                float* __restrict__ Cout)
{
    __shared__ unsigned short As[64 * 64];
    __shared__ unsigned short Bs[96 * 64];
    gemm_body(A, Wt, bias, Cout, 2, 1.0f, As, Bs);
}

// ---------------------------------------------------------------------------
// Flash attention, swapped-QK^T 32x32 MFMA, exp2-domain, defer-max.
// r16 wave-private structure + r17 FIX: __syncthreads() between the kv-loop
// and the merge overlays (r16's mlx sat inside wave-3's live staging region
// and was clobbered concurrently -> NaN). Loop stays zero-barrier and
// wave-private (race-free by construction).
// ---------------------------------------------------------------------------
__global__ __launch_bounds__(256, 4) void attn_mfma(const unsigned short* __restrict__ Q,
                                                    const unsigned short* __restrict__ K,
                                                    const unsigned short* __restrict__ Vt,
                                                    unsigned short* __restrict__ O)
{
    // Loop phase: wave w region = bytes [w*8192, w*8192+8192): K 4KB + V 4KB.
    // Post-loop overlays (ALL strictly after the loop-exit barrier):
    //   pub  float[3][32][64]  bytes [0,24576)   (rotation-swizzled rows)
    //   mlx  float2[4][32]     bytes [24576,25600)
    //   Ep   uint[32][33]      bytes [0,4224)    (wave-0 only, after pub consumed)
    __shared__ __align__(16) char shraw[32768];
    unsigned short* shus = (unsigned short*)shraw;
    float*          pub  = (float*)shraw;
    float2*         mlx  = (float2*)(shraw + 24576);
    unsigned int*   Ep   = (unsigned int*)shraw;

    const int tid = threadIdx.x;
    const int l = tid & 63, w = tid >> 6;    // wave = kv split
    const int l31 = l & 31, hi = l >> 5;
    const int q0 = blockIdx.x * 32;
    const int h = blockIdx.y, b = blockIdx.z;
    const size_t base = ((size_t)b * NHEADS + h) * (size_t)SEQ * HDIM;

    unsigned short* Kb = shus + w * 4096;    // 2048 shorts K
    unsigned short* Vb = Kb + 2048;          // 2048 shorts V (interleaved layout)

    // Q fragments (B-operand): col q = l&31, k(d) = 16t + 8hi + i
    const int q = q0 + l31;
    bf16x8 qf[4];
#pragma unroll
    for (int t = 0; t < 4; ++t)
        qf[t] = *reinterpret_cast<const bf16x8*>(&Q[base + (size_t)q * HDIM + 16 * t + 8 * hi]);

    f32x16 accO[2] = {};      // O^T partial: rows d = 32*db + crow(r,hi), col q = l31
    float m = -1e30f, lsum = 0.f;

    const int klr = l >> 3, kslot = l & 7;   // K staging lane decomposition
    const int vdl = l & 15, vjs = l >> 4;    // V staging lane decomposition

    for (int t = 0; t < 16; ++t) {
        const int t0 = w * (SEQ / 4) + t * 32;

        // all prior ds_reads of this buffer done before DMA overwrite
        asm volatile("s_waitcnt lgkmcnt(0)" ::: "memory");
        // K tile [32 kv][64 d], 4 chunks x 8 rows, source col inverse-swizzled
#pragma unroll
        for (int c = 0; c < 4; ++c) {
            const int row = c * 8 + klr;
            const int sl = kslot ^ (row & 7);
            gl_lds16(&K[base + (size_t)(t0 + row) * HDIM + sl * 8], &Kb[c * 512]);
        }
        // V tile [64 d][32 j], interleaved: content (d = c*16+vdl, j8 = vjs)
        // lands at shorts (vjs*16 + (d&15))*8 within chunk c (read-side aware)
#pragma unroll
        for (int c = 0; c < 4; ++c) {
            gl_lds16(&Vt[base + (size_t)(c * 16 + vdl) * SEQ + t0 + vjs * 8], &Vb[c * 512]);
        }
        asm volatile("s_waitcnt vmcnt(0)" ::: "memory");   // own loads landed
        __builtin_amdgcn_sched_barrier(0);

        // S^T (32 kv x 32 q): lane holds q=l31, kv = (r&3)+8*(r>>2)+4*hi
        f32x16 sv = {};
        __builtin_amdgcn_s_setprio(1);
#pragma unroll
        for (int tt = 0; tt < 4; ++tt) {
            const int co = 16 * tt + 8 * hi;
            const bf16x8 kf = *reinterpret_cast<const bf16x8*>(&Kb[l31 * 64 + (co ^ ((l31 & 7) << 3))]);
            sv = __builtin_amdgcn_mfma_f32_32x32x16_bf16(kf, qf[tt], sv, 0, 0, 0);
        }
        __builtin_amdgcn_s_setprio(0);

        // max (4-wide groups) + cross-half combine
        float tmax = -1e30f;
#pragma unroll
        for (int r = 0; r < 16; r += 4)
            tmax = fmaxf(tmax, fmaxf(fmaxf(sv[r], sv[r + 1]), fmaxf(sv[r + 2], sv[r + 3])));
        tmax = fmaxf(tmax, __shfl_xor(tmax, 32));

        // defer-max (T13): rescale only when tile max grows > 8 (exp2 domain)
        if (tmax > m + 8.f) {
            const float scl = fast_exp2(m - tmax);
            lsum *= scl;
#pragma unroll
            for (int r = 0; r < 16; ++r) { accO[0][r] *= scl; accO[1][r] *= scl; }
            m = tmax;
        }

        // fused exp -> HW bf16 pack
        unsigned wv[8];
        float ls = 0.f;
#pragma unroll
        for (int a = 0; a < 8; ++a) {
            const float pa = fast_exp2(sv[2 * a] - m);
            const float pb = fast_exp2(sv[2 * a + 1] - m);
            ls += pa + pb;
            wv[a] = cvtpk_bf16(pa, pb);
        }
        ls += __shfl_xor(ls, 32);
        lsum += ls;

        // PV: 2 k-slots of 16 kv; B-frag via half-swap; 2 d-block MFMAs each
#pragma unroll
        for (int s2 = 0; s2 < 2; ++s2) {
            const unsigned w0 = wv[s2 * 4 + 0], w1 = wv[s2 * 4 + 1];
            const unsigned w2 = wv[s2 * 4 + 2], w3 = wv[s2 * 4 + 3];
            const unsigned x0 = (unsigned)__shfl_xor((int)w0, 32);
            const unsigned x1 = (unsigned)__shfl_xor((int)w1, 32);
            const unsigned x2 = (unsigned)__shfl_xor((int)w2, 32);
            const unsigned x3 = (unsigned)__shfl_xor((int)w3, 32);
            uint4 fr;
            fr.x = hi ? x2 : w0;   // kv 16*s2 + 8*hi + {0,1}
            fr.y = hi ? x3 : w1;   // {2,3}
            fr.z = hi ? w2 : x0;   // {4,5}
            fr.w = hi ? w3 : x1;   // {6,7}
            const bf16x8 pfrag = __builtin_bit_cast(bf16x8, fr);
            __builtin_amdgcn_s_setprio(1);
#pragma unroll
            for (int db = 0; db < 2; ++db) {
                const int d = 32 * db + l31;
                const int js = 2 * s2 + hi;
                const bf16x8 vf = *reinterpret_cast<const bf16x8*>(
                    &Vb[(d >> 4) * 512 + (js * 16 + (d & 15)) * 8]);
                accO[db] = __builtin_amdgcn_mfma_f32_32x32x16_bf16(vf, pfrag, accO[db], 0, 0, 0);
            }
            __builtin_amdgcn_s_setprio(0);
        }
    }

    // ---- 4-way flash merge ----
    __syncthreads();                         // THE FIX: all waves done with
                                             // staging before any overlay write
    if (!hi) mlx[w * 32 + l31] = make_float2(m, lsum);
    __syncthreads();                         // mlx visible to all waves
    float M = -1e30f;
    float mj[4], lj[4];
#pragma unroll
    for (int j = 0; j < 4; ++j) {
        const float2 tml = mlx[j * 32 + l31];
        mj[j] = tml.x; lj[j] = tml.y;
        M = fmaxf(M, tml.x);
    }
    float lf = 0.f;
#pragma unroll
    for (int j = 0; j < 4; ++j) lf += lj[j] * fast_exp2(mj[j] - M);
    const float s = fast_exp2(m - M);
    const float inv = 1.f / lf;

    if (w != 0) {                            // publish scaled partial (rotation swizzle)
#pragma unroll
        for (int db = 0; db < 2; ++db)
#pragma unroll
            for (int r = 0; r < 16; ++r) {
                const int d = 32 * db + (r & 3) + 8 * (r >> 2) + 4 * hi;
                pub[(w - 1) * 2048 + l31 * 64 + ((d + l31) & 63)] = accO[db][r] * s;
            }
    }
    __syncthreads();                         // pub visible; waves 1-3 exit after
    if (w == 0) {
#pragma unroll
        for (int db = 0; db < 2; ++db)
#pragma unroll
            for (int r = 0; r < 16; ++r) {
                const int d = 32 * db + (r & 3) + 8 * (r >> 2) + 4 * hi;
                float v = accO[db][r] * s;
#pragma unroll
                for (int wi = 0; wi < 3; ++wi)
                    v += pub[wi * 2048 + l31 * 64 + ((d + l31) & 63)];
                accO[db][r] = v * inv;
            }
        asm volatile("s_waitcnt lgkmcnt(0)" ::: "memory");   // pub reads done
        __builtin_amdgcn_sched_barrier(0);
#pragma unroll
        for (int db = 0; db < 2; ++db)
#pragma unroll
            for (int a = 0; a < 8; ++a) {
                const unsigned wd = packbf2(accO[db][2 * a], accO[db][2 * a + 1]);
                const int pi = 16 * db + 4 * (a >> 1) + (a & 1) + 2 * hi;
                Ep[l31 * 33 + pi] = wd;
            }
        asm volatile("s_waitcnt lgkmcnt(0)" ::: "memory");   // Ep writes committed
        __builtin_amdgcn_sched_barrier(0);
#pragma unroll
        for (int pss = 0; pss < 4; ++pss) {
            const int idx = pss * 64 + l;
            const int qr = idx >> 3, c = idx & 7;
            uint4 ov;
            ov.x = Ep[qr * 33 + c * 4 + 0];
            ov.y = Ep[qr * 33 + c * 4 + 1];
            ov.z = Ep[qr * 33 + c * 4 + 2];
            ov.w = Ep[qr * 33 + c * 4 + 3];
            *reinterpret_cast<uint4*>(&O[((size_t)b * SEQ + q0 + qr) * HIDDEN + h * HDIM + c * 8]) = ov;
        }
    }
}

// ---------------------------------------------------------------------------
extern "C" void kernel_launch(void* const* d_in, const int* in_sizes, int n_in,
                              void* d_out, int out_size, void* d_ws, size_t ws_size,
                              hipStream_t stream)
{
    const float* x  = (const float*)d_in[0];
    const float* Wq = (const float*)d_in[1];
    const float* bq = (const float*)d_in[2];
    const float* Wk = (const float*)d_in[3];
    const float* bk = (const float*)d_in[4];
    const float* Wv = (const float*)d_in[5];
    const float* bv = (const float*)d_in[6];
    const float* Wo = (const float*)d_in[7];
    const float* bo = (const float*)d_in[8];
    float* out = (float*)d_out;

    unsigned short* p = (unsigned short*)d_ws;
    const size_t szX = (size_t)NROWS * HIDDEN;
    const size_t szW = (size_t)HIDDEN * HIDDEN;
    const size_t szH = (size_t)BATCH * NHEADS * SEQ * HDIM;
    unsigned short* xb  = p;              p += szX;
    unsigned short* Wqt = p;              p += szW;
    unsigned short* Wkt = p;              p += szW;
    unsigned short* Wvt = p;              p += szW;
    unsigned short* Wot = p;              p += szW;
    unsigned short* Qb  = p;              p += szH;
    unsigned short* Kb  = p;              p += szH;
    unsigned short* Vtb = p;              p += szH;
    unsigned short* Oab = p;              p += szX;

    cvt_bf16<<<(int)(szX / 4 + 255) / 256, 256, 0, stream>>>(x, xb, (int)(szX / 4));
    transpose_cvt4<<<dim3(HIDDEN / 64, HIDDEN / 64, 4), 256, 0, stream>>>(
        Wq, Wk, Wv, Wo, Wqt, Wkt, Wvt, Wot);

    qkv_gemm<<<dim3(HIDDEN / 96, NROWS / 64, 3), 256, 0, stream>>>(
        xb, Wqt, Wkt, Wvt, bq, bk, bv, Qb, Kb, Vtb);

    attn_mfma<<<dim3(SEQ / 32, NHEADS, BATCH), 256, 0, stream>>>(Qb, Kb, Vtb, Oab);

    out_gemm<<<dim3(HIDDEN / 96, NROWS / 64), 256, 0, stream>>>(Oab, Wot, bo, out);
}